// Round 4
// baseline (808.230 us; speedup 1.0000x reference)
//
#include <hip/hip_runtime.h>

#define HDIM 128
#define SEQ  14
#define G4   512
#define TLEN 8
#define NTHR 512
#define HPITCH 160   // halves per elem row (320 B): elem0 banks 0-15, elem1 banks 16-31

typedef _Float16 half8 __attribute__((ext_vector_type(8)));
typedef float f32x4 __attribute__((ext_vector_type(4)));
typedef float f32x2 __attribute__((ext_vector_type(2)));

#define LOG2E  1.44269504f
#define LOG2E2 2.88539008f

__device__ __forceinline__ float frcp_(float x) { return __builtin_amdgcn_rcpf(x); }
#if defined(__has_builtin)
#if __has_builtin(__builtin_amdgcn_exp2f)
#define EXP2_(x) __builtin_amdgcn_exp2f(x)
#endif
#endif
#ifndef EXP2_
#define EXP2_(x) __expf((x) * 0.69314718f)
#endif
// inputs pre-scaled by log2e (sig) / 2*log2e (tanh):
__device__ __forceinline__ float fsigP_(float y)  { return frcp_(1.0f + EXP2_(-y)); }
__device__ __forceinline__ float ftanhP_(float y) { return 1.0f - 2.0f * frcp_(EXP2_(y) + 1.0f); }
// unscaled (scores path):
__device__ __forceinline__ float ftanh_(float x)  { return ftanhP_(x * LOG2E2); }

// Per-pair (2 batch elements) LDS state. Two pairs per block: the two
// recurrences are independent, so each barrier interval advances BOTH pairs
// one LSTM step — one exposed ds_read latency, one barrier, and one epilogue
// tail amortized over two steps, while pair A's MFMA chains fill the matrix
// pipe during pair B's serial tail (and vice versa).
struct __align__(16) PairMem {
    _Float16 h2[2][2][HPITCH];             // [buf][elem][col], bank-colored
    _Float16 ench[SEQ][2][HPITCH];         // encoder outputs, bank-colored
    _Float16 encWe[SEQ][2][HDIM];          // enc_out @ We
    _Float16 hWdh[2][HDIM];                // h @ Wd
    __align__(16) float ctx2[HDIM + 1][2]; // [s][e]; row 128 = x
    __align__(16) float inp2[SEQ][2];
    float attnw[2][SEQ];
    float asum[2][SEQ];
    float score[2][SEQ];
};

struct __align__(16) SMem {
    __align__(16) float zq[4];             // persistent zero quad (opaque to compiler)
    PairMem P[2];
    float wv[HDIM];
    float wf[HDIM];
};

struct AFrag { half8 a0, a1, a2, a3; };

__device__ __forceinline__ AFrag lstm_read(const _Float16* __restrict__ srcBase, int q, int l) {
    const _Float16* sp = srcBase + ((l >> 2) & 1) * HPITCH + 8 * q;
    AFrag f;
    f.a0 = *(const half8*)(sp);
    f.a1 = *(const half8*)(sp + 32);
    f.a2 = *(const half8*)(sp + 64);
    f.a3 = *(const half8*)(sp + 96);
    return f;
}

// One LSTM step for 2 batch elements (one pair). A-row r carries elem
// (r>>2)&1, so for writer lanes q<2, D reg0 (= row 4q) is the lane's own
// element's gate value. Chained (D=C) K-accumulation per gate — accumulator
// forwarding makes dependent MFMA chains cheap (R1: splitting them onto the
// VALU cost +19%). Weights pre-scaled by log2e (i,f,o) / 2*log2e (g) for
// bare v_exp_f32. Caller must __syncthreads() after.
__device__ __forceinline__ float lstm_compute(
    const AFrag& f,
    _Float16* __restrict__ dstw,           // &h2[nxt][q][16w+l] (q<2)
    f32x2 xv, f32x4 zeroq,
    const half8 (&whh)[4][4], const float (&wih)[4], const float (&bia)[4],
    float& c, int q)
{
    f32x4 A[4];
    #pragma unroll
    for (int g = 0; g < 4; ++g) {
        A[g] = __builtin_amdgcn_mfma_f32_16x16x32_f16(f.a0, whh[g][0], zeroq, 0, 0, 0);
        A[g] = __builtin_amdgcn_mfma_f32_16x16x32_f16(f.a1, whh[g][1], A[g], 0, 0, 0);
        A[g] = __builtin_amdgcn_mfma_f32_16x16x32_f16(f.a2, whh[g][2], A[g], 0, 0, 0);
        A[g] = __builtin_amdgcn_mfma_f32_16x16x32_f16(f.a3, whh[g][3], A[g], 0, 0, 0);
    }
    float hn = 0.0f;
    if (q < 2) {                           // writer lanes; reg0 = own element
        float x = (q & 1) ? xv[1] : xv[0];
        float ig = fsigP_(fmaf(x, wih[0], bia[0]) + A[0][0]);
        float fg = fsigP_(fmaf(x, wih[1], bia[1]) + A[1][0]);
        float gg = ftanhP_(fmaf(x, wih[2], bia[2]) + A[2][0]);
        float og = fsigP_(fmaf(x, wih[3], bia[3]) + A[3][0]);
        c = fmaf(fg, c, ig * gg);
        hn = og * ftanhP_(c * LOG2E2);
        *dstw = (_Float16)hn;
    }
    return hn;
}

__global__ __launch_bounds__(NTHR, 2) void seq2seq_kernel(
    const float* __restrict__ inputs,
    const float* __restrict__ Wih_e, const float* __restrict__ Whh_e, const float* __restrict__ b_e,
    const float* __restrict__ Wih_d, const float* __restrict__ Whh_d, const float* __restrict__ b_d,
    const float* __restrict__ We, const float* __restrict__ Wd,
    const float* __restrict__ Wv, const float* __restrict__ Wf, const float* __restrict__ bfp,
    float* __restrict__ out, int B)
{
    const int tid  = threadIdx.x;
    const int b0   = blockIdx.x * 4;       // 4 elems per block = 2 pairs
    const int w    = tid >> 6;
    const int lane = tid & 63;
    const int q    = lane >> 4;
    const int l    = lane & 15;
    const int wrcol = 16 * w + l;
    __shared__ SMem S;

    const _Float16* s0A = &S.P[0].h2[0][0][0];
    const _Float16* s1A = &S.P[0].h2[1][0][0];
    const _Float16* s0B = &S.P[1].h2[0][0][0];
    const _Float16* s1B = &S.P[1].h2[1][0][0];
    _Float16* d0A = &S.P[0].h2[0][q & 1][wrcol];
    _Float16* d1A = &S.P[0].h2[1][q & 1][wrcol];
    _Float16* d0B = &S.P[1].h2[0][q & 1][wrcol];
    _Float16* d1B = &S.P[1].h2[1][q & 1][wrcol];

    // gate scales: i,f,o -> log2e ; g -> 2*log2e
    const float gscale[4] = {LOG2E, LOG2E, LOG2E2, LOG2E};

    // ---- init ----
    if (tid < 4) S.zq[tid] = 0.0f;
    for (int idx = tid; idx < 2 * 2 * 2 * HDIM; idx += NTHR) {  // 2 pairs x 2 bufs x 2 elems x 128
        int p = idx >> 9, r = idx & 511;
        int buf = r >> 8, e = (r >> 7) & 1, j = r & 127;
        S.P[p].h2[buf][e][j] = (_Float16)0.0f;
    }
    if (tid < SEQ * 4) {
        int t = tid >> 2, mm = tid & 3;
        int p = mm >> 1, m = mm & 1;
        S.P[p].inp2[t][m] = inputs[(b0 + mm) * SEQ + t];
        S.P[p].asum[m][t] = 0.0f;
    }
    if (tid < HDIM) { S.wv[tid] = Wv[tid]; S.wf[tid] = Wf[tid]; }
    if (tid < 4) S.P[tid >> 1].ctx2[HDIM][tid & 1] = inputs[(b0 + tid) * SEQ + (SEQ - 1)];

    // ---- encoder weights (B-frags, pre-scaled; shared by both pairs) ----
    half8 whh[4][4];
    float wih[4], bia[4];
    #pragma unroll
    for (int g = 0; g < 4; ++g) {
        int n = g * HDIM + wrcol;
        float sc = gscale[g];
        wih[g] = Wih_e[n] * sc;
        bia[g] = b_e[n] * sc;
        #pragma unroll
        for (int kt = 0; kt < 4; ++kt) {
            half8 f;
            #pragma unroll
            for (int jj = 0; jj < 8; ++jj)
                f[jj] = (_Float16)(Whh_e[(32 * kt + 8 * q + jj) * G4 + n] * sc);
            whh[g][kt] = f;
        }
    }
    float cA = 0.0f, cB = 0.0f;
    __syncthreads();

    const f32x4 zeroq = *(const f32x4*)S.zq;   // opaque zeros: 4 persistent VGPRs

    // ---- encoder: 14 steps (7 static-parity pairs), both pairs per barrier ----
    f32x2 xvA = *(const f32x2*)&S.P[0].inp2[0][0];
    f32x2 xvB = *(const f32x2*)&S.P[1].inp2[0][0];
    for (int t = 0; t < SEQ; t += 2) {
        AFrag fA = lstm_read(s0A, q, l);
        AFrag fB = lstm_read(s0B, q, l);
        float hnA = lstm_compute(fA, d1A, xvA, zeroq, whh, wih, bia, cA, q);
        float hnB = lstm_compute(fB, d1B, xvB, zeroq, whh, wih, bia, cB, q);
        if (q < 2) {
            S.P[0].ench[t][q][wrcol] = (_Float16)hnA;
            S.P[1].ench[t][q][wrcol] = (_Float16)hnB;
        }
        xvA = *(const f32x2*)&S.P[0].inp2[t + 1][0];
        xvB = *(const f32x2*)&S.P[1].inp2[t + 1][0];
        __syncthreads();
        fA = lstm_read(s1A, q, l);
        fB = lstm_read(s1B, q, l);
        hnA = lstm_compute(fA, d0A, xvA, zeroq, whh, wih, bia, cA, q);
        hnB = lstm_compute(fB, d0B, xvB, zeroq, whh, wih, bia, cB, q);
        if (q < 2) {
            S.P[0].ench[t + 1][q][wrcol] = (_Float16)hnA;
            S.P[1].ench[t + 1][q][wrcol] = (_Float16)hnB;
        }
        if (t + 2 < SEQ) {
            xvA = *(const f32x2*)&S.P[0].inp2[t + 2][0];
            xvB = *(const f32x2*)&S.P[1].inp2[t + 2][0];
        }
        __syncthreads();
    }
    // h now in h2[0] for both pairs

    // ---- encWe = enc_out @ We (one-time; unscaled weights) ----
    {
        half8 wef[4];
        #pragma unroll
        for (int kt = 0; kt < 4; ++kt) {
            half8 f;
            #pragma unroll
            for (int jj = 0; jj < 8; ++jj)
                f[jj] = (_Float16)We[(32 * kt + 8 * q + jj) * HDIM + wrcol];
            wef[kt] = f;
        }
        for (int t = 0; t < SEQ; ++t) {
            #pragma unroll
            for (int p = 0; p < 2; ++p) {
                const _Float16* er = &S.P[p].ench[t][0][0] + ((l >> 2) & 1) * HPITCH + 8 * q;
                half8 e0 = *(const half8*)(er);
                half8 e1 = *(const half8*)(er + 32);
                half8 e2 = *(const half8*)(er + 64);
                half8 e3 = *(const half8*)(er + 96);
                f32x4 dv = __builtin_amdgcn_mfma_f32_16x16x32_f16(e0, wef[0], zeroq, 0, 0, 0);
                dv = __builtin_amdgcn_mfma_f32_16x16x32_f16(e1, wef[1], dv, 0, 0, 0);
                dv = __builtin_amdgcn_mfma_f32_16x16x32_f16(e2, wef[2], dv, 0, 0, 0);
                dv = __builtin_amdgcn_mfma_f32_16x16x32_f16(e3, wef[3], dv, 0, 0, 0);
                if (q < 2) S.P[p].encWe[t][q][wrcol] = (_Float16)dv[0];  // reg0 = row 4q = elem q
            }
        }
    }

    // ---- decoder weights (pre-scaled; shared by both pairs) ----
    half8 wdf[4];
    #pragma unroll
    for (int g = 0; g < 4; ++g) {
        int n = g * HDIM + wrcol;
        float sc = gscale[g];
        wih[g] = Wih_d[n] * sc;
        bia[g] = b_d[n] * sc;
        #pragma unroll
        for (int kt = 0; kt < 4; ++kt) {
            half8 f;
            #pragma unroll
            for (int jj = 0; jj < 8; ++jj)
                f[jj] = (_Float16)(Whh_d[(32 * kt + 8 * q + jj) * G4 + n] * sc);
            whh[g][kt] = f;
        }
    }
    #pragma unroll
    for (int kt = 0; kt < 4; ++kt) {
        half8 f;
        #pragma unroll
        for (int jj = 0; jj < 8; ++jj)
            f[jj] = (_Float16)Wd[(32 * kt + 8 * q + jj) * HDIM + wrcol];
        wdf[kt] = f;
    }
    float bf0 = bfp[0];
    __syncthreads();   // encWe + x0 visible

    // ---- decoder: 8 steps, parity alternates (h enters in h2[0]) ----
    #pragma unroll 1
    for (int dd = 0; dd < TLEN; ++dd) {
        const bool even = (dd & 1) == 0;
        const _Float16* sCA = even ? s0A : s1A;
        const _Float16* sOA = even ? s1A : s0A;
        const _Float16* sCB = even ? s0B : s1B;
        const _Float16* sOB = even ? s1B : s0B;
        _Float16* dCA = even ? d0A : d1A;
        _Float16* dOA = even ? d1A : d0A;
        _Float16* dCB = even ? d0B : d1B;
        _Float16* dOB = even ? d1B : d0B;

        // hWd = h @ Wd (chained), both pairs
        {
            AFrag fA = lstm_read(sCA, q, l);
            AFrag fB = lstm_read(sCB, q, l);
            f32x4 dvA = __builtin_amdgcn_mfma_f32_16x16x32_f16(fA.a0, wdf[0], zeroq, 0, 0, 0);
            dvA = __builtin_amdgcn_mfma_f32_16x16x32_f16(fA.a1, wdf[1], dvA, 0, 0, 0);
            dvA = __builtin_amdgcn_mfma_f32_16x16x32_f16(fA.a2, wdf[2], dvA, 0, 0, 0);
            dvA = __builtin_amdgcn_mfma_f32_16x16x32_f16(fA.a3, wdf[3], dvA, 0, 0, 0);
            f32x4 dvB = __builtin_amdgcn_mfma_f32_16x16x32_f16(fB.a0, wdf[0], zeroq, 0, 0, 0);
            dvB = __builtin_amdgcn_mfma_f32_16x16x32_f16(fB.a1, wdf[1], dvB, 0, 0, 0);
            dvB = __builtin_amdgcn_mfma_f32_16x16x32_f16(fB.a2, wdf[2], dvB, 0, 0, 0);
            dvB = __builtin_amdgcn_mfma_f32_16x16x32_f16(fB.a3, wdf[3], dvB, 0, 0, 0);
            if (q < 2) {
                S.P[0].hWdh[q][wrcol] = (_Float16)dvA[0];
                S.P[1].hWdh[q][wrcol] = (_Float16)dvB[0];
            }
        }
        __syncthreads();
        // scores: 56 rows (pair,elem,t) x 8 lanes, 16 cols per lane
        if (tid < 4 * SEQ * 8) {
            int p8 = tid >> 3, sub = tid & 7;
            int mm = p8 & 3, t = p8 >> 2;
            int p = mm >> 1, m = mm & 1;
            float s = 0.0f;
            #pragma unroll
            for (int i = 0; i < 16; ++i) {
                int j = sub * 16 + i;
                s = fmaf(ftanh_((float)S.P[p].encWe[t][m][j] + (float)S.P[p].hWdh[m][j]), S.wv[j], s);
            }
            s += __shfl_down(s, 4, 8);
            s += __shfl_down(s, 2, 8);
            s += __shfl_down(s, 1, 8);
            if (sub == 0) S.P[p].score[m][t] = s;
        }
        __syncthreads();
        // softmax over 14 per element (4 elements)
        if (tid < 4) {
            int p = tid >> 1, m = tid & 1;
            float sc[SEQ]; float mx = -1e30f;
            #pragma unroll
            for (int t = 0; t < SEQ; ++t) { sc[t] = S.P[p].score[m][t]; mx = fmaxf(mx, sc[t]); }
            float ssum = 0.0f;
            #pragma unroll
            for (int t = 0; t < SEQ; ++t) { float e = __expf(sc[t] - mx); sc[t] = e; ssum += e; }
            float inv = frcp_(ssum);
            #pragma unroll
            for (int t = 0; t < SEQ; ++t) {
                float a = sc[t] * inv;
                S.P[p].attnw[m][t] = a;
                S.P[p].asum[m][t] += a;
            }
        }
        __syncthreads();
        // context -> ctx2[j][e]; all 512 threads = 4 elems x 128 cols
        {
            int e4 = tid >> 7, j = tid & 127;
            int p = e4 >> 1, e = e4 & 1;
            float a = 0.0f;
            #pragma unroll
            for (int t = 0; t < SEQ; ++t)
                a = fmaf(S.P[p].attnw[e][t], (float)S.P[p].ench[t][e][j], a);
            S.P[p].ctx2[j][e] = a;
        }
        __syncthreads();

        // decoder LSTM: 129 steps = 64 static-parity pairs + 1; both pairs
        // advance per barrier; x prefetched
        const f32x2* xpA = (const f32x2*)&S.P[0].ctx2[0][0];
        const f32x2* xpB = (const f32x2*)&S.P[1].ctx2[0][0];
        f32x2 xdA = xpA[0];
        f32x2 xdB = xpB[0];
        #pragma unroll 1
        for (int s2 = 0; s2 < 64; ++s2) {
            AFrag fA = lstm_read(sCA, q, l);
            AFrag fB = lstm_read(sCB, q, l);
            (void)lstm_compute(fA, dOA, xdA, zeroq, whh, wih, bia, cA, q);
            (void)lstm_compute(fB, dOB, xdB, zeroq, whh, wih, bia, cB, q);
            xdA = xpA[2 * s2 + 1];         // issued before the barrier
            xdB = xpB[2 * s2 + 1];
            __syncthreads();
            fA = lstm_read(sOA, q, l);
            fB = lstm_read(sOB, q, l);
            (void)lstm_compute(fA, dCA, xdA, zeroq, whh, wih, bia, cA, q);
            (void)lstm_compute(fB, dCB, xdB, zeroq, whh, wih, bia, cB, q);
            xdA = xpA[2 * s2 + 2];         // s2=63 -> xp[128] = x row, valid
            xdB = xpB[2 * s2 + 2];
            __syncthreads();
        }
        {
            AFrag fA = lstm_read(sCA, q, l);
            AFrag fB = lstm_read(sCB, q, l);
            (void)lstm_compute(fA, dOA, xdA, zeroq, whh, wih, bia, cA, q);
            (void)lstm_compute(fB, dOB, xdB, zeroq, whh, wih, bia, cB, q);
        }
        __syncthreads();
        // h now in the "other" buffer; output projection -> next x (4 elems)
        if (tid < 64) {
            int m4 = tid >> 4, part = tid & 15;
            int p = m4 >> 1, m = m4 & 1;
            const _Float16* hO = even ? &S.P[p].h2[1][0][0] : &S.P[p].h2[0][0][0];
            half8 hv = *(const half8*)(hO + m * HPITCH + part * 8);
            float s = 0.0f;
            #pragma unroll
            for (int i = 0; i < 8; ++i) s = fmaf((float)hv[i], S.wf[part * 8 + i], s);
            s += __shfl_down(s, 8, 16);
            s += __shfl_down(s, 4, 16);
            s += __shfl_down(s, 2, 16);
            s += __shfl_down(s, 1, 16);
            if (part == 0) {
                float o = s + bf0;
                out[(b0 + m4) * TLEN + dd] = o;
                S.P[p].ctx2[HDIM][m] = o;
            }
        }
        __syncthreads();
    }

    // total_attn [B, 14, 1] for 4 elems
    if (tid < 4 * SEQ) {
        int m4 = tid / SEQ, t = tid % SEQ;
        out[B * TLEN + (b0 + m4) * SEQ + t] = S.P[m4 >> 1].asum[m4 & 1][t];
    }
}

extern "C" void kernel_launch(void* const* d_in, const int* in_sizes, int n_in,
                              void* d_out, int out_size, void* d_ws, size_t ws_size,
                              hipStream_t stream) {
    const float* inputs = (const float*)d_in[0];
    const float* Wih_e = (const float*)d_in[2];
    const float* Whh_e = (const float*)d_in[3];
    const float* b_e   = (const float*)d_in[4];
    const float* Wih_d = (const float*)d_in[5];
    const float* Whh_d = (const float*)d_in[6];
    const float* b_d   = (const float*)d_in[7];
    const float* We    = (const float*)d_in[8];
    const float* Wd    = (const float*)d_in[9];
    const float* Wv    = (const float*)d_in[10];
    const float* Wf    = (const float*)d_in[11];
    const float* bfp   = (const float*)d_in[12];
    float* out = (float*)d_out;

    const int B = in_sizes[0] / SEQ;  // 512

    seq2seq_kernel<<<dim3(B / 4), dim3(NTHR), 0, stream>>>(
        inputs, Wih_e, Whh_e, b_e, Wih_d, Whh_d, b_d, We, Wd, Wv, Wf, bfp, out, B);
}